// Round 24
// baseline (61.627 us; speedup 1.0000x reference)
//
#include <hip/hip_runtime.h>
#include <hip/hip_bf16.h>

#define N 8192
#define D 128
#define NSPLIT 16
#define KVSPLIT (N / NSPLIT)   // 512 keys per block
#define KVBLK 64
#define NT (KVSPLIT / KVBLK)   // 8 tiles
#define L2E 1.442695041f

typedef __attribute__((ext_vector_type(8))) _Float16 half8;
typedef __attribute__((ext_vector_type(2))) __fp16 fp16x2;
typedef __attribute__((ext_vector_type(16))) float f32x16;

union H8 { fp16x2 h2[4]; half8 h8; };

__device__ __forceinline__ float fexp2(float x) {
    float r; asm("v_exp_f32 %0, %1" : "=v"(r) : "v"(x)); return r;
}

// ---- fused preprocessing: Q cvt (blocks 0-511), K cvt (512-1023), V transpose (1024-1279)
// V [N][D] fp32 -> Vtp [D][N] fp16, k-permuted per 32-block:
// slot s32 = 16*(k>>4) + 8*((k>>2)&1) + 4*((k>>3)&1) + (k&3) holds key k (within 32-group)
__global__ void prep_kernel(const float* __restrict__ Q, const float* __restrict__ K,
                            const float* __restrict__ V, _Float16* __restrict__ Qh,
                            _Float16* __restrict__ Kh, _Float16* __restrict__ Vtp) {
    __shared__ _Float16 tile[64][65];
    const int bid = blockIdx.x;
    const int tid = threadIdx.x;
    if (bid < 1024) {
        const float4* src = (const float4*)(bid < 512 ? Q : K);
        _Float16* dst = (bid < 512) ? Qh : Kh;
        const int b = bid & 511;
#pragma unroll
        for (int p = 0; p < 2; ++p) {
            int i = b * 512 + p * 256 + tid;
            float4 v = src[i];
            ushort4 o;
            o.x = __builtin_bit_cast(ushort, (_Float16)v.x);
            o.y = __builtin_bit_cast(ushort, (_Float16)v.y);
            o.z = __builtin_bit_cast(ushort, (_Float16)v.z);
            o.w = __builtin_bit_cast(ushort, (_Float16)v.w);
            *reinterpret_cast<ushort4*>(dst + (size_t)i * 4) = o;
        }
    } else {
        const int vbid = bid - 1024;
        const int k0 = (vbid & 127) * 64;
        const int d0 = (vbid >> 7) * 64;
#pragma unroll
        for (int p = 0; p < 16; ++p) {
            int flat = p * 256 + tid;
            int r = flat >> 6, cc = flat & 63;
            tile[r][cc] = (_Float16)(V[(size_t)(k0 + r) * D + d0 + cc]);
        }
        __syncthreads();
#pragma unroll
        for (int p = 0; p < 16; ++p) {
            int flat = p * 256 + tid;
            int dd = flat >> 6, kl = flat & 63;
            int kk = kl & 31;
            int s32 = 16 * (kk >> 4) + 8 * ((kk >> 2) & 1) + 4 * ((kk >> 3) & 1) + (kk & 3);
            Vtp[(size_t)(d0 + dd) * N + k0 + (kl & 32) + s32] = tile[kl][dd];
        }
    }
}

// ---- stage K tile (64 keys, 16KB) / V tile into LDS (256 threads; linear dest,
// inv-swizzled src). K pos = (ch&8) | ((ch&7)^(row&7)); V pos = ch ^ (d&7).
#define STAGE_K(kdst_, kbase_)                                                        \
    {                                                                                 \
        _Pragma("unroll")                                                             \
        for (int p = 0; p < 4; ++p) {                                                 \
            int c4 = p * 256 + tid;                                                   \
            int row = c4 >> 4, chs = c4 & 15;                                         \
            int cc = (chs & 8) | ((chs & 7) ^ (row & 7));                             \
            __builtin_amdgcn_global_load_lds(                                         \
                (const __attribute__((address_space(1))) void*)(Kh + (size_t)((kbase_) + row) * D + cc * 8), \
                (__attribute__((address_space(3))) void*)((kdst_) + c4 * 8), 16, 0, 0);              \
        }                                                                             \
    }
#define STAGE_V(vdst_, kbase_)                                                        \
    {                                                                                 \
        _Pragma("unroll")                                                             \
        for (int p = 0; p < 4; ++p) {                                                 \
            int c4 = p * 256 + tid;                                                   \
            int dd = c4 >> 3, chs = c4 & 7;                                           \
            int cc = chs ^ (dd & 7);                                                  \
            __builtin_amdgcn_global_load_lds(                                         \
                (const __attribute__((address_space(1))) void*)(Vtp + (size_t)dd * N + (kbase_) + cc * 8),   \
                (__attribute__((address_space(3))) void*)((vdst_) + c4 * 8), 16, 0, 0);              \
        }                                                                             \
    }

// PV step over one 32-key S-tile (16 keys per ks sub-step).
// A = V-fragment (row = d), B = P-fragment (col = q = lane&31)
#define PVSTEP(Pv, ktc)                                                               \
    _Pragma("unroll")                                                                 \
    for (int ks = 0; ks < 2; ++ks) {                                                  \
        H8 u;                                                                         \
        u.h2[0] = __builtin_amdgcn_cvt_pkrtz(Pv[ks * 8 + 0], Pv[ks * 8 + 1]);         \
        u.h2[1] = __builtin_amdgcn_cvt_pkrtz(Pv[ks * 8 + 2], Pv[ks * 8 + 3]);         \
        u.h2[2] = __builtin_amdgcn_cvt_pkrtz(Pv[ks * 8 + 4], Pv[ks * 8 + 5]);         \
        u.h2[3] = __builtin_amdgcn_cvt_pkrtz(Pv[ks * 8 + 6], Pv[ks * 8 + 7]);         \
        int ch = (ktc) * 4 + ks * 2 + h;                                              \
        _Pragma("unroll")                                                             \
        for (int dt = 0; dt < 4; ++dt) {                                              \
            int dd = dt * 32 + c;                                                     \
            int pos = ch ^ (dd & 7);                                                  \
            half8 vf = *reinterpret_cast<const half8*>(vb + dd * 64 + pos * 8);       \
            oacc[dt] = __builtin_amdgcn_mfma_f32_32x32x16_f16(vf, u.h8, oacc[dt], 0, 0, 0); \
        }                                                                             \
    }

// ---- main kernel: 4 waves x 32 q-rows, KVBLK=64, K dbuf (32KB) + V single (16KB)
// = 48KB -> 3 blocks/CU (12 waves, 3 independent barrier groups). V(t) staged at
// iteration top, lands under QK+softmax, drained by the mid-iteration barrier.
__launch_bounds__(256, 2)
__global__ void fa_kernel(const _Float16* __restrict__ Qh, const _Float16* __restrict__ Kh,
                          const _Float16* __restrict__ Vtp, _Float16* __restrict__ Oph,
                          float* __restrict__ Mpart, float* __restrict__ Lpart) {
    __shared__ __align__(16) _Float16 smem[24576];  // K dbuf 2x8192 + V 8192 halfs

    const int tid  = threadIdx.x;
    const int w    = tid >> 6;
    const int lane = tid & 63;
    const int h    = lane >> 5;    // lane half
    const int c    = lane & 31;    // q-col (QK), key-row (K A-frag), d-col (PV A-frag)
    const int bid  = blockIdx.x;
    const int split = bid & (NSPLIT - 1);   // XCD = bid%8 -> split pinned to one L2
    const int bx   = bid >> 4;
    const int q0w  = bx * 128 + w * 32;
    const int kv0  = split * KVSPLIT;

    _Float16* const vb = smem + 16384;

    // Q fragments: qa[st] = Q[q0w + c][st*16 + h*8 .. +7]  (B-operand of swapped QK)
    half8 qa[8];
    {
        const _Float16* qrow = Qh + (size_t)(q0w + c) * D + h * 8;
#pragma unroll
        for (int st = 0; st < 8; ++st)
            qa[st] = *reinterpret_cast<const half8*>(qrow + st * 16);
    }

    f32x16 oacc[4];
#pragma unroll
    for (int dt = 0; dt < 4; ++dt)
#pragma unroll
        for (int r = 0; r < 16; ++r) oacc[dt][r] = 0.f;
    float mrun = -1e30f, lrun = 0.f;

    STAGE_K(smem, kv0);
    __syncthreads();

    for (int t = 0; t < NT; ++t) {
        const int cur = t & 1;
        const _Float16* kb = smem + cur * 8192;

        // V(t) into the single buffer (overwrite ordered by previous end barrier);
        // K(t+1) prefetch as before. Both land under QK+softmax.
        STAGE_V(vb, kv0 + t * KVBLK);
        if (t + 1 < NT)
            STAGE_K(smem + (cur ^ 1) * 8192, kv0 + (t + 1) * KVBLK);

        // ---- S^T = K Q^T : lane holds S[key=crow(reg,h)][q=c] for 2 k-tiles of 32 ----
        f32x16 sb0, sb1;
#pragma unroll
        for (int r = 0; r < 16; ++r) { sb0[r] = 0.f; sb1[r] = 0.f; }
#pragma unroll
        for (int st = 0; st < 8; ++st) {
            int ch = st * 2 + h;
            int pos = (ch & 8) | ((ch & 7) ^ (c & 7));
            half8 kf0 = *reinterpret_cast<const half8*>(kb + c * 128 + pos * 8);
            half8 kf1 = *reinterpret_cast<const half8*>(kb + (32 + c) * 128 + pos * 8);
            sb0 = __builtin_amdgcn_mfma_f32_32x32x16_f16(kf0, qa[st], sb0, 0, 0, 0);
            sb1 = __builtin_amdgcn_mfma_f32_32x32x16_f16(kf1, qa[st], sb1, 0, 0, 0);
        }

        // ---- in-register online softmax (per lane: one q, 32 of 64 keys) ----
        float pmax = sb0[0];
#pragma unroll
        for (int r = 1; r < 16; ++r) pmax = fmaxf(pmax, sb0[r]);
#pragma unroll
        for (int r = 0; r < 16; ++r) pmax = fmaxf(pmax, sb1[r]);
        pmax = fmaxf(pmax, __shfl_xor(pmax, 32));   // merge lane pair: all 64 keys

        if (!__all(pmax <= mrun + 8.0f)) {   // defer-max (T13)
            float nm = fmaxf(mrun, pmax);
            float scl = __expf(mrun - nm);
            lrun *= scl;
#pragma unroll
            for (int dt = 0; dt < 4; ++dt)
#pragma unroll
                for (int r = 0; r < 16; ++r) oacc[dt][r] *= scl;
            mrun = nm;
        }
        float tsum = 0.f;
#pragma unroll
        for (int r = 0; r < 16; ++r) { sb0[r] = __expf(sb0[r] - mrun); tsum += sb0[r]; }
#pragma unroll
        for (int r = 0; r < 16; ++r) { sb1[r] = __expf(sb1[r] - mrun); tsum += sb1[r]; }
        lrun += tsum + __shfl_xor(tsum, 32);

        __syncthreads();   // V(t) landed (vmcnt drained), all waves aligned for PV

        // ---- O += P V  (A = V from LDS, B = P packed in-register) ----
        PVSTEP(sb0, 0)
        PVSTEP(sb1, 1)

        __syncthreads();   // all waves done with vb & kb before next iter's stages
    }

    // ---- epilogue: normalize, transpose via LDS (overlay), coalesced fp16 store ----
    // Fully unrolled: oacc indexing must stay compile-time (rule #20 scratch trap).
    float inv = 1.0f / lrun;
    float* epi = reinterpret_cast<float*>(smem) + w * 1088;   // 32x33 f32 per wave
    const size_t sbase = (size_t)split * N;
#pragma unroll
    for (int dt = 0; dt < 4; ++dt) {
#pragma unroll
        for (int r = 0; r < 16; ++r) {
            int dloc = (r & 3) + 8 * (r >> 2) + 4 * h;
            epi[c * 33 + dloc] = oacc[dt][r] * inv;   // epi[q_local][d_local]
        }
#pragma unroll
        for (int it = 0; it < 16; ++it) {
            int j = it * 64 + lane;
            int rr = j >> 5, cc2 = j & 31;
            Oph[(sbase + q0w + rr) * D + dt * 32 + cc2] = (_Float16)epi[rr * 33 + cc2];
        }
    }
    if (h == 0) {
        Mpart[sbase + q0w + c] = mrun;
        Lpart[sbase + q0w + c] = lrun;
    }
}

// ---- merge the NSPLIT partials (vectorized: 4 d-elements/thread, G13) ----
__global__ void fa_merge(const _Float16* __restrict__ Oph, const float* __restrict__ Mpart,
                         const float* __restrict__ Lpart, float* __restrict__ O) {
    int idx = blockIdx.x * 256 + threadIdx.x;   // over N*D/4
    int q = idx >> 5;          // 32 quads per 128-wide row
    int d4 = (idx & 31) * 4;
    float m[NSPLIT];
    float M = -1e30f;
#pragma unroll
    for (int s = 0; s < NSPLIT; ++s) {
        m[s] = Mpart[s * N + q];
        M = fmaxf(M, m[s]);
    }
    float acc0 = 0.f, acc1 = 0.f, acc2 = 0.f, acc3 = 0.f, wsum = 0.f;
#pragma unroll
    for (int s = 0; s < NSPLIT; ++s) {
        float wgt = fexp2((m[s] - M) * L2E) * Lpart[s * N + q];
        wsum += wgt;
        ushort4 v = *reinterpret_cast<const ushort4*>(Oph + ((size_t)s * N + q) * D + d4);
        acc0 += wgt * (float)__builtin_bit_cast(_Float16, v.x);
        acc1 += wgt * (float)__builtin_bit_cast(_Float16, v.y);
        acc2 += wgt * (float)__builtin_bit_cast(_Float16, v.z);
        acc3 += wgt * (float)__builtin_bit_cast(_Float16, v.w);
    }
    float invw = 1.0f / wsum;
    float4 out;
    out.x = acc0 * invw; out.y = acc1 * invw; out.z = acc2 * invw; out.w = acc3 * invw;
    *reinterpret_cast<float4*>(O + (size_t)q * D + d4) = out;
}

extern "C" void kernel_launch(void* const* d_in, const int* in_sizes, int n_in,
                              void* d_out, int out_size, void* d_ws, size_t ws_size,
                              hipStream_t stream) {
    const float* Q = (const float*)d_in[0];
    const float* K = (const float*)d_in[1];
    const float* V = (const float*)d_in[2];
    float* O = (float*)d_out;

    _Float16* Qh = (_Float16*)d_ws;                         // 2 MB
    _Float16* Kh = Qh + (size_t)N * D;                      // 2 MB
    _Float16* Vtp = Kh + (size_t)N * D;                     // 2 MB
    _Float16* Oph = Vtp + (size_t)N * D;                    // 32 MB (fp16 partials x16)
    float* Mpart = (float*)(Oph + (size_t)NSPLIT * N * D);  // 512 KB
    float* Lpart = Mpart + (size_t)NSPLIT * N;              // 512 KB

    hipLaunchKernelGGL(prep_kernel, dim3(1280), dim3(256), 0, stream,
                       Q, K, V, Qh, Kh, Vtp);
    hipLaunchKernelGGL(fa_kernel, dim3((N / 128) * NSPLIT), dim3(256), 0, stream,
                       Qh, Kh, Vtp, Oph, Mpart, Lpart);
    hipLaunchKernelGGL(fa_merge, dim3(N * D / 4 / 256), dim3(256), 0, stream,
                       Oph, Mpart, Lpart, O);
}

// Round 25
// 56.670 us; speedup vs baseline: 1.0875x; 1.0875x over previous
//
#include <hip/hip_runtime.h>
#include <hip/hip_bf16.h>

#define N 8192
#define D 128
#define NSPLIT 8
#define KVSPLIT (N / NSPLIT)   // 1024 keys per block
#define KVBLK 64
#define NT (KVSPLIT / KVBLK)   // 16 tiles
#define L2E 1.442695041f

typedef __attribute__((ext_vector_type(8))) _Float16 half8;
typedef __attribute__((ext_vector_type(2))) __fp16 fp16x2;
typedef __attribute__((ext_vector_type(16))) float f32x16;

union H8 { fp16x2 h2[4]; half8 h8; };

__device__ __forceinline__ float fexp2(float x) {
    float r; asm("v_exp_f32 %0, %1" : "=v"(r) : "v"(x)); return r;
}

// ---- fused preprocessing: Q cvt (blocks 0-511), K cvt (512-1023), V transpose (1024-1279)
// V [N][D] fp32 -> Vtp [D][N] fp16, k-permuted per 32-block:
// slot s32 = 16*(k>>4) + 8*((k>>2)&1) + 4*((k>>3)&1) + (k&3) holds key k (within 32-group)
__global__ void prep_kernel(const float* __restrict__ Q, const float* __restrict__ K,
                            const float* __restrict__ V, _Float16* __restrict__ Qh,
                            _Float16* __restrict__ Kh, _Float16* __restrict__ Vtp) {
    __shared__ _Float16 tile[64][65];
    const int bid = blockIdx.x;
    const int tid = threadIdx.x;
    if (bid < 1024) {
        const float4* src = (const float4*)(bid < 512 ? Q : K);
        _Float16* dst = (bid < 512) ? Qh : Kh;
        const int b = bid & 511;
#pragma unroll
        for (int p = 0; p < 2; ++p) {
            int i = b * 512 + p * 256 + tid;
            float4 v = src[i];
            ushort4 o;
            o.x = __builtin_bit_cast(ushort, (_Float16)v.x);
            o.y = __builtin_bit_cast(ushort, (_Float16)v.y);
            o.z = __builtin_bit_cast(ushort, (_Float16)v.z);
            o.w = __builtin_bit_cast(ushort, (_Float16)v.w);
            *reinterpret_cast<ushort4*>(dst + (size_t)i * 4) = o;
        }
    } else {
        const int vbid = bid - 1024;
        const int k0 = (vbid & 127) * 64;
        const int d0 = (vbid >> 7) * 64;
#pragma unroll
        for (int p = 0; p < 16; ++p) {
            int flat = p * 256 + tid;
            int r = flat >> 6, cc = flat & 63;
            tile[r][cc] = (_Float16)(V[(size_t)(k0 + r) * D + d0 + cc]);
        }
        __syncthreads();
#pragma unroll
        for (int p = 0; p < 16; ++p) {
            int flat = p * 256 + tid;
            int dd = flat >> 6, kl = flat & 63;
            int kk = kl & 31;
            int s32 = 16 * (kk >> 4) + 8 * ((kk >> 2) & 1) + 4 * ((kk >> 3) & 1) + (kk & 3);
            Vtp[(size_t)(d0 + dd) * N + k0 + (kl & 32) + s32] = tile[kl][dd];
        }
    }
}

// ---- stage one 64-key K/V tile into LDS (256 threads; linear dest, inv-swizzled src)
// K: [64 k][128 d], 16B chunk ch, stored pos = (ch&8) | ((ch&7)^(row&7))
// V: [128 d][64 slot], 8 chunks/row, stored pos = ch ^ (d&7)
#define STAGE(kdst_, vdst_, kbase_)                                                   \
    {                                                                                 \
        _Pragma("unroll")                                                             \
        for (int p = 0; p < 4; ++p) {                                                 \
            int c4 = p * 256 + tid;                                                   \
            int row = c4 >> 4, chs = c4 & 15;                                         \
            int cc = (chs & 8) | ((chs & 7) ^ (row & 7));                             \
            __builtin_amdgcn_global_load_lds(                                         \
                (const __attribute__((address_space(1))) void*)(Kh + (size_t)((kbase_) + row) * D + cc * 8), \
                (__attribute__((address_space(3))) void*)((kdst_) + c4 * 8), 16, 0, 0);              \
        }                                                                             \
        _Pragma("unroll")                                                             \
        for (int p = 0; p < 4; ++p) {                                                 \
            int c4 = p * 256 + tid;                                                   \
            int dd = c4 >> 3, chs = c4 & 7;                                           \
            int cc = chs ^ (dd & 7);                                                  \
            __builtin_amdgcn_global_load_lds(                                         \
                (const __attribute__((address_space(1))) void*)(Vtp + (size_t)dd * N + (kbase_) + cc * 8),   \
                (__attribute__((address_space(3))) void*)((vdst_) + c4 * 8), 16, 0, 0);              \
        }                                                                             \
    }

// PV step over one 32-key S-tile (16 keys per ks sub-step).
// A = V-fragment (row = d), B = P-fragment (col = q = lane&31)
// => D[m=d][n=q]: oacc[dt][r] = O[q=c][d = dt*32 + crow(r,h)]  -- q on LANE axis.
#define PVSTEP(Pv, ktc)                                                               \
    _Pragma("unroll")                                                                 \
    for (int ks = 0; ks < 2; ++ks) {                                                  \
        H8 u;                                                                         \
        u.h2[0] = __builtin_amdgcn_cvt_pkrtz(Pv[ks * 8 + 0], Pv[ks * 8 + 1]);         \
        u.h2[1] = __builtin_amdgcn_cvt_pkrtz(Pv[ks * 8 + 2], Pv[ks * 8 + 3]);         \
        u.h2[2] = __builtin_amdgcn_cvt_pkrtz(Pv[ks * 8 + 4], Pv[ks * 8 + 5]);         \
        u.h2[3] = __builtin_amdgcn_cvt_pkrtz(Pv[ks * 8 + 6], Pv[ks * 8 + 7]);         \
        int ch = (ktc) * 4 + ks * 2 + h;                                              \
        _Pragma("unroll")                                                             \
        for (int dt = 0; dt < 4; ++dt) {                                              \
            int dd = dt * 32 + c;                                                     \
            int pos = ch ^ (dd & 7);                                                  \
            half8 vf = *reinterpret_cast<const half8*>(vb + dd * 64 + pos * 8);       \
            oacc[dt] = __builtin_amdgcn_mfma_f32_32x32x16_f16(vf, u.h8, oacc[dt], 0, 0, 0); \
        }                                                                             \
    }

// ---- main kernel: verified best configuration (fa 51.6 us, VGPR 104) ----
// 4 waves x 32 q-rows (128 q/block), KVBLK=64, 64KB double-buffer, plain
// __syncthreads, serial-chain softmax + __expf, immediate PV, no setprio.
__launch_bounds__(256, 2)
__global__ void fa_kernel(const _Float16* __restrict__ Qh, const _Float16* __restrict__ Kh,
                          const _Float16* __restrict__ Vtp, _Float16* __restrict__ Oph,
                          float* __restrict__ Mpart, float* __restrict__ Lpart) {
    __shared__ __align__(16) _Float16 smem[32768];  // K dbuf 2x16KB, V dbuf 2x16KB

    const int tid  = threadIdx.x;
    const int w    = tid >> 6;
    const int lane = tid & 63;
    const int h    = lane >> 5;    // lane half
    const int c    = lane & 31;    // q-col (QK), key-row (K A-frag), d-col (PV A-frag)
    const int bid  = blockIdx.x;
    const int split = bid & 7;     // block i -> XCD i%8: split pinned to one XCD's L2
    const int bx   = bid >> 3;
    const int q0w  = bx * 128 + w * 32;
    const int kv0  = split * KVSPLIT;

    // Q fragments: qa[st] = Q[q0w + c][st*16 + h*8 .. +7]  (B-operand of swapped QK)
    half8 qa[8];
    {
        const _Float16* qrow = Qh + (size_t)(q0w + c) * D + h * 8;
#pragma unroll
        for (int st = 0; st < 8; ++st)
            qa[st] = *reinterpret_cast<const half8*>(qrow + st * 16);
    }

    f32x16 oacc[4];
#pragma unroll
    for (int dt = 0; dt < 4; ++dt)
#pragma unroll
        for (int r = 0; r < 16; ++r) oacc[dt][r] = 0.f;
    float mrun = -1e30f, lrun = 0.f;

    STAGE(smem, smem + 16384, kv0);
    __syncthreads();

    for (int t = 0; t < NT; ++t) {
        const int cur = t & 1;
        if (t + 1 < NT)
            STAGE(smem + (cur ^ 1) * 8192, smem + 16384 + (cur ^ 1) * 8192,
                  kv0 + (t + 1) * KVBLK);

        const _Float16* kb = smem + cur * 8192;
        const _Float16* vb = smem + 16384 + cur * 8192;

        // ---- S^T = K Q^T : lane holds S[key=crow(reg,h)][q=c] for 2 k-tiles of 32 ----
        f32x16 sb0, sb1;
#pragma unroll
        for (int r = 0; r < 16; ++r) { sb0[r] = 0.f; sb1[r] = 0.f; }
#pragma unroll
        for (int st = 0; st < 8; ++st) {
            int ch = st * 2 + h;
            int pos = (ch & 8) | ((ch & 7) ^ (c & 7));
            half8 kf0 = *reinterpret_cast<const half8*>(kb + c * 128 + pos * 8);
            half8 kf1 = *reinterpret_cast<const half8*>(kb + (32 + c) * 128 + pos * 8);
            sb0 = __builtin_amdgcn_mfma_f32_32x32x16_f16(kf0, qa[st], sb0, 0, 0, 0);
            sb1 = __builtin_amdgcn_mfma_f32_32x32x16_f16(kf1, qa[st], sb1, 0, 0, 0);
        }

        // ---- in-register online softmax (per lane: one q, 32 of 64 keys) ----
        float pmax = sb0[0];
#pragma unroll
        for (int r = 1; r < 16; ++r) pmax = fmaxf(pmax, sb0[r]);
#pragma unroll
        for (int r = 0; r < 16; ++r) pmax = fmaxf(pmax, sb1[r]);
        pmax = fmaxf(pmax, __shfl_xor(pmax, 32));   // merge lane pair: all 64 keys

        if (!__all(pmax <= mrun + 8.0f)) {   // defer-max (T13)
            float nm = fmaxf(mrun, pmax);
            float scl = __expf(mrun - nm);
            lrun *= scl;
#pragma unroll
            for (int dt = 0; dt < 4; ++dt)
#pragma unroll
                for (int r = 0; r < 16; ++r) oacc[dt][r] *= scl;
            mrun = nm;
        }
        float tsum = 0.f;
#pragma unroll
        for (int r = 0; r < 16; ++r) { sb0[r] = __expf(sb0[r] - mrun); tsum += sb0[r]; }
#pragma unroll
        for (int r = 0; r < 16; ++r) { sb1[r] = __expf(sb1[r] - mrun); tsum += sb1[r]; }
        lrun += tsum + __shfl_xor(tsum, 32);

        // ---- O += P V  (A = V from LDS, B = P packed in-register) ----
        PVSTEP(sb0, 0)
        PVSTEP(sb1, 1)

        __syncthreads();
    }

    // ---- epilogue: normalize, transpose via LDS (overlay), coalesced fp16 store ----
    // Fully unrolled: oacc indexing must stay compile-time (rule #20 scratch trap).
    __syncthreads();   // all waves done with K/V buffers
    float inv = 1.0f / lrun;
    float* epi = reinterpret_cast<float*>(smem) + w * 1088;   // 32x33 f32 per wave
    const size_t sbase = (size_t)split * N;
#pragma unroll
    for (int dt = 0; dt < 4; ++dt) {
#pragma unroll
        for (int r = 0; r < 16; ++r) {
            int dloc = (r & 3) + 8 * (r >> 2) + 4 * h;
            epi[c * 33 + dloc] = oacc[dt][r] * inv;   // epi[q_local][d_local]
        }
#pragma unroll
        for (int it = 0; it < 16; ++it) {
            int j = it * 64 + lane;
            int rr = j >> 5, cc2 = j & 31;
            Oph[(sbase + q0w + rr) * D + dt * 32 + cc2] = (_Float16)epi[rr * 33 + cc2];
        }
    }
    if (h == 0) {
        Mpart[sbase + q0w + c] = mrun;
        Lpart[sbase + q0w + c] = lrun;
    }
}

// ---- merge the NSPLIT partials (vectorized: 4 d-elements/thread, G13) ----
__global__ void fa_merge(const _Float16* __restrict__ Oph, const float* __restrict__ Mpart,
                         const float* __restrict__ Lpart, float* __restrict__ O) {
    int idx = blockIdx.x * 256 + threadIdx.x;   // over N*D/4
    int q = idx >> 5;          // 32 quads per 128-wide row
    int d4 = (idx & 31) * 4;
    float m[NSPLIT];
    float M = -1e30f;
#pragma unroll
    for (int s = 0; s < NSPLIT; ++s) {
        m[s] = Mpart[s * N + q];
        M = fmaxf(M, m[s]);
    }
    float acc0 = 0.f, acc1 = 0.f, acc2 = 0.f, acc3 = 0.f, wsum = 0.f;
#pragma unroll
    for (int s = 0; s < NSPLIT; ++s) {
        float wgt = fexp2((m[s] - M) * L2E) * Lpart[s * N + q];
        wsum += wgt;
        ushort4 v = *reinterpret_cast<const ushort4*>(Oph + ((size_t)s * N + q) * D + d4);
        acc0 += wgt * (float)__builtin_bit_cast(_Float16, v.x);
        acc1 += wgt * (float)__builtin_bit_cast(_Float16, v.y);
        acc2 += wgt * (float)__builtin_bit_cast(_Float16, v.z);
        acc3 += wgt * (float)__builtin_bit_cast(_Float16, v.w);
    }
    float invw = 1.0f / wsum;
    float4 out;
    out.x = acc0 * invw; out.y = acc1 * invw; out.z = acc2 * invw; out.w = acc3 * invw;
    *reinterpret_cast<float4*>(O + (size_t)q * D + d4) = out;
}

extern "C" void kernel_launch(void* const* d_in, const int* in_sizes, int n_in,
                              void* d_out, int out_size, void* d_ws, size_t ws_size,
                              hipStream_t stream) {
    const float* Q = (const float*)d_in[0];
    const float* K = (const float*)d_in[1];
    const float* V = (const float*)d_in[2];
    float* O = (float*)d_out;

    _Float16* Qh = (_Float16*)d_ws;                         // 2 MB
    _Float16* Kh = Qh + (size_t)N * D;                      // 2 MB
    _Float16* Vtp = Kh + (size_t)N * D;                     // 2 MB
    _Float16* Oph = Vtp + (size_t)N * D;                    // 16 MB (fp16 partials x8)
    float* Mpart = (float*)(Oph + (size_t)NSPLIT * N * D);  // 256 KB
    float* Lpart = Mpart + (size_t)NSPLIT * N;              // 256 KB

    hipLaunchKernelGGL(prep_kernel, dim3(1280), dim3(256), 0, stream,
                       Q, K, V, Qh, Kh, Vtp);
    hipLaunchKernelGGL(fa_kernel, dim3((N / 128) * NSPLIT), dim3(256), 0, stream,
                       Qh, Kh, Vtp, Oph, Mpart, Lpart);
    hipLaunchKernelGGL(fa_merge, dim3(N * D / 4 / 256), dim3(256), 0, stream,
                       Oph, Mpart, Lpart, O);
}